// Round 8
// baseline (177.597 us; speedup 1.0000x reference)
//
#include <hip/hip_runtime.h>
#include <float.h>
#include <stdint.h>

#define T_ 2048
#define DG 256   // folded/group width: 4 groups * 64

typedef _Float16 half8 __attribute__((ext_vector_type(8)));
typedef _Float16 half4v __attribute__((ext_vector_type(4)));
typedef __fp16 fp16x2 __attribute__((ext_vector_type(2)));
typedef float f32x4 __attribute__((ext_vector_type(4)));
typedef float f32x16 __attribute__((ext_vector_type(16)));
typedef unsigned uint2v __attribute__((ext_vector_type(2)));

__device__ __forceinline__ void gload16(const void* g, void* l) {
  __builtin_amdgcn_global_load_lds(
      (const __attribute__((address_space(1))) unsigned int*)g,
      (__attribute__((address_space(3))) unsigned int*)l, 16, 0, 0);
}
#define WAIT_LGKM0() do { asm volatile("s_waitcnt lgkmcnt(0)" ::: "memory"); __builtin_amdgcn_sched_barrier(0); } while (0)

// lane<->lane^32 exchange, all-VALU (v_permlane32_swap_b32)
__device__ __forceinline__ float cross32(float x, int g) {
  unsigned u = __builtin_bit_cast(unsigned, x);
  uint2v r = __builtin_amdgcn_permlane32_swap(u, u, false, false);
  return __builtin_bit_cast(float, g ? r[0] : r[1]);
}

// ---- prep_w: Wt[768][1024] fp16 (folded Wq | Wk | Wv, transposed) + bcat[768] f32 ----
__global__ __launch_bounds__(256) void prep_w(
    const float* __restrict__ Wq, const float* __restrict__ bq,
    const float* __restrict__ Wk, const float* __restrict__ bk,
    const float* __restrict__ Wv, const float* __restrict__ bv,
    _Float16* __restrict__ Wt, float* __restrict__ bcat) {
  int idx = blockIdx.x * 256 + threadIdx.x;   // 786432
  int n = idx >> 10, k = idx & 1023;
  float v;
  if (n < 256)      v = Wq[k * 1024 + n] + Wq[k * 1024 + n + 256]
                      + Wq[k * 1024 + n + 512] + Wq[k * 1024 + n + 768];
  else if (n < 512) v = Wk[k * 256 + n - 256];
  else              v = Wv[k * 256 + n - 512];
  Wt[idx] = (_Float16)v;
  if (k == 0) {
    float bb;
    if (n < 256)      bb = bq[n] + bq[n + 256] + bq[n + 512] + bq[n + 768];
    else if (n < 512) bb = bk[n - 256];
    else              bb = bv[n - 512];
    bcat[n] = bb;
  }
}

// ---- qkv_gemm: x[16384x1024] fp32 @ Wt^T -> Q fp16(x log2e) | K fp16 | V^T fp16 ----
// 128x256 tile (2 n-tiles/block, grid y=3): halves x re-read traffic vs y=6.
__global__ __launch_bounds__(256) void qkv_gemm(
    const float* __restrict__ x, const _Float16* __restrict__ Wt,
    const float* __restrict__ bcat,
    _Float16* __restrict__ Qh, _Float16* __restrict__ Kh, _Float16* __restrict__ Vt) {
  __shared__ __align__(16) uint8_t smem[65536];   // 2 x (A 16KB fp32 + B 16KB fp16)
  const int tid = threadIdx.x;
  const int w = tid >> 6, l = tid & 63;
  const int wr = w >> 1, wc = w & 1;
  const int lr = l & 15, lk = l >> 4;
  const int m0 = blockIdx.x * 128;
  const int by = blockIdx.y;          // 0=Q, 1=K, 2=V
  const int n0 = by * 256;

  f32x4 acc[4][8] = {};

  auto stage = [&](int k0, int buf) {
    uint8_t* Ab = smem + buf * 32768;
    uint8_t* Bb = Ab + 16384;
    // A: 128 rows x 32 fp32 (1024 slots of 16B), XOR-preswizzled source
#pragma unroll
    for (int i = 0; i < 4; ++i) {
      int si = i * 256 + tid;
      int row = si >> 3, p = si & 7;
      gload16(x + (size_t)(m0 + row) * 1024 + k0 + ((p ^ (row & 7)) << 2), Ab + si * 16);
    }
    // B: 256 rows x 32 fp16 (1024 slots of 16B)
#pragma unroll
    for (int i = 0; i < 4; ++i) {
      int si = i * 256 + tid;
      int row = si >> 2, p = si & 3;
      gload16(Wt + (size_t)(n0 + row) * 1024 + k0 + ((p ^ (row & 3)) << 3), Bb + si * 16);
    }
  };

  stage(0, 0);
  __syncthreads();

  for (int kt = 0; kt < 32; ++kt) {
    int cur = kt & 1;
    if (kt < 31) stage((kt + 1) * 32, cur ^ 1);
    const uint8_t* Ab = smem + cur * 32768;
    const uint8_t* Bb = Ab + 16384;
    half8 af[4], bf[8];
#pragma unroll
    for (int mi = 0; mi < 4; ++mi) {
      int row = wr * 64 + mi * 16 + lr;
      const float* pa = (const float*)(Ab + row * 128);
      f32x4 a0 = *(const f32x4*)(pa + ((((lk << 1))     ^ (row & 7)) << 2));
      f32x4 a1 = *(const f32x4*)(pa + ((((lk << 1) | 1) ^ (row & 7)) << 2));
      half8 h;
#pragma unroll
      for (int j = 0; j < 4; ++j) { h[j] = (_Float16)a0[j]; h[j + 4] = (_Float16)a1[j]; }
      af[mi] = h;
    }
#pragma unroll
    for (int ni = 0; ni < 8; ++ni) {
      int row = wc * 128 + ni * 16 + lr;
      bf[ni] = *(const half8*)(Bb + row * 64 + ((lk ^ (row & 3)) << 4));
    }
#pragma unroll
    for (int mi = 0; mi < 4; ++mi)
#pragma unroll
      for (int ni = 0; ni < 8; ++ni)
        acc[mi][ni] = __builtin_amdgcn_mfma_f32_16x16x32_f16(af[mi], bf[ni], acc[mi][ni], 0, 0, 0);
    __syncthreads();
  }

  // ---- epilogue: C col = lane&15 (n), row = (lane>>4)*4 + r (m) ----
#pragma unroll
  for (int mi = 0; mi < 4; ++mi) {
#pragma unroll
    for (int ni = 0; ni < 8; ++ni) {
      int nl = wc * 128 + ni * 16 + lr;           // 0..255 within this type
      int mg = m0 + wr * 64 + mi * 16 + lk * 4;
      float bias = bcat[n0 + nl];
      if (by == 0) {
#pragma unroll
        for (int r = 0; r < 4; ++r)
          Qh[(size_t)(mg + r) * DG + nl] = (_Float16)((acc[mi][ni][r] + bias) * 1.44269504f);
      } else if (by == 1) {
#pragma unroll
        for (int r = 0; r < 4; ++r)
          Kh[(size_t)(mg + r) * DG + nl] = (_Float16)(acc[mi][ni][r] + bias);
      } else {
        half4v h;
#pragma unroll
        for (int r = 0; r < 4; ++r) h[r] = (_Float16)(acc[mi][ni][r] + bias);
        *(half4v*)(Vt + ((size_t)((mg >> 11) * DG + nl)) * T_ + (mg & 2047)) = h;
      }
    }
  }
}

// ---- fused causal attention: 4 waves/WG KV-split, K & V direct from L2, LDS = merge only ----
__global__ __launch_bounds__(256) void attn_mfma(
    const _Float16* __restrict__ Qg, const _Float16* __restrict__ Kg,
    const _Float16* __restrict__ Vtg, float* __restrict__ out) {
  __shared__ __align__(16) uint8_t smem[67584];   // 2 x 32KB dump + 2KB m/l
  const int tid = threadIdx.x;
  const int wv = tid >> 6;        // 0..3
  const int l  = tid & 63;
  const int g  = l >> 5;
  const int ln = l & 31;
  const int bid = blockIdx.x;
  const int b   = bid & 7;                 // batch -> XCD pinning
  const int tile = (bid < 256) ? (63 - (bid >> 3)) : ((bid - 256) >> 3);
  const int q0 = tile * 32;

  const _Float16* Kb = Kg  + (size_t)b * T_ * DG;
  const _Float16* Vb = Vtg + (size_t)b * DG * T_;

  const _Float16* Qrow = Qg + ((size_t)(b * T_ + q0 + ln)) * DG + 8 * g;
  half8 qf[16];
#pragma unroll
  for (int kk = 0; kk < 16; ++kk) qf[kk] = *(const half8*)(Qrow + kk * 16);

  f32x16 o[8] = {};
  float m_r = -1e30f, l_r = 0.0f;

  for (int kt = wv; kt <= tile; kt += 4) {
    int s0 = kt * 32;
    // ---- K fragments direct from L2: lane ln owns row s0+ln, 16B chunks ----
    const _Float16* krow = Kb + (size_t)(s0 + ln) * DG + 8 * g;
    half8 kf[16];
#pragma unroll
    for (int kk = 0; kk < 16; ++kk) kf[kk] = *(const half8*)(krow + kk * 16);

    f32x16 sa = {}, sb = {};
    __builtin_amdgcn_s_setprio(1);
#pragma unroll
    for (int kk = 0; kk < 16; kk += 2) {
      sa = __builtin_amdgcn_mfma_f32_32x32x16_f16(kf[kk],     qf[kk],     sa, 0, 0, 0);
      sb = __builtin_amdgcn_mfma_f32_32x32x16_f16(kf[kk + 1], qf[kk + 1], sb, 0, 0, 0);
    }
    __builtin_amdgcn_s_setprio(0);

    // V fragments: issue now, consumed after softmax (L2 latency hidden there)
    half8 vf0[8], vf1[8];
#pragma unroll
    for (int dt = 0; dt < 8; ++dt) {
      const _Float16* vr = Vb + (size_t)(dt * 32 + ln) * T_ + s0 + 8 * g;
      vf0[dt] = *(const half8*)vr;
      vf1[dt] = *(const half8*)(vr + 16);
    }

    float s[16];
#pragma unroll
    for (int r = 0; r < 16; ++r) s[r] = sa[r] + sb[r];
    if (kt == tile) {                // causal mask, diagonal tile only
#pragma unroll
      for (int r = 0; r < 16; ++r) {
        int srow = (r & 3) + 8 * (r >> 2) + 4 * g;
        if (srow > ln) s[r] = -1e30f;
      }
    }
    float pmax = s[0];
#pragma unroll
    for (int r = 1; r < 16; ++r) pmax = fmaxf(pmax, s[r]);
    pmax = fmaxf(pmax, cross32(pmax, g));
    if (!__all(pmax <= m_r + 8.0f)) {   // defer-max rescale (T13)
      float mnew = fmaxf(m_r, pmax);
      float sc = __builtin_amdgcn_exp2f(m_r - mnew);
      l_r *= sc;
#pragma unroll
      for (int dt = 0; dt < 8; ++dt)
#pragma unroll
        for (int r = 0; r < 16; ++r) o[dt][r] *= sc;
      m_r = mnew;
    }
    float p[16]; float psum = 0.0f;
#pragma unroll
    for (int r = 0; r < 16; ++r) { p[r] = __builtin_amdgcn_exp2f(s[r] - m_r); psum += p[r]; }
    l_r += psum + cross32(psum, g);

    // ---- P -> fp16 B-fragments: cvt_pkrtz + 4 permlane32_swap ----
    unsigned ph[8];
#pragma unroll
    for (int i = 0; i < 8; ++i) {
      fp16x2 t2 = __builtin_amdgcn_cvt_pkrtz(p[2 * i], p[2 * i + 1]);
      ph[i] = __builtin_bit_cast(unsigned, t2);
    }
    union U { unsigned u[4]; half8 h; };
    U f0, f1;
    {
      uint2v r02 = __builtin_amdgcn_permlane32_swap(ph[0], ph[2], false, false);
      uint2v r13 = __builtin_amdgcn_permlane32_swap(ph[1], ph[3], false, false);
      uint2v r46 = __builtin_amdgcn_permlane32_swap(ph[4], ph[6], false, false);
      uint2v r57 = __builtin_amdgcn_permlane32_swap(ph[5], ph[7], false, false);
      f0.u[0] = r02[0]; f0.u[2] = r02[1];
      f0.u[1] = r13[0]; f0.u[3] = r13[1];
      f1.u[0] = r46[0]; f1.u[2] = r46[1];
      f1.u[1] = r57[0]; f1.u[3] = r57[1];
    }

    __builtin_amdgcn_s_setprio(1);
#pragma unroll
    for (int dt = 0; dt < 8; ++dt)
      o[dt] = __builtin_amdgcn_mfma_f32_32x32x16_f16(vf0[dt], f0.h, o[dt], 0, 0, 0);
#pragma unroll
    for (int dt = 0; dt < 8; ++dt)
      o[dt] = __builtin_amdgcn_mfma_f32_32x32x16_f16(vf1[dt], f1.h, o[dt], 0, 0, 0);
    __builtin_amdgcn_s_setprio(0);
  }

  // ---- tree merge: (1->0, 3->2) then (2->0); dump buffers 2 x 32KB, m/l at +65536 ----
  float* ml = (float*)(smem + 65536);     // [wave][2][64]
  __syncthreads();
  if (wv & 1) {                            // waves 1,3 dump
    float* dst = (float*)(smem + (wv >> 1) * 32768);
#pragma unroll
    for (int dt = 0; dt < 8; ++dt)
#pragma unroll
      for (int r = 0; r < 16; ++r)
        dst[(dt * 16 + r) * 64 + l] = o[dt][r];
    ml[wv * 128 + l]      = m_r;
    ml[wv * 128 + 64 + l] = l_r;
  }
  __syncthreads();
  if (!(wv & 1)) {                         // waves 0,2 merge partner wv+1
    float m1 = ml[(wv + 1) * 128 + l];
    float l1 = ml[(wv + 1) * 128 + 64 + l];
    float M   = fmaxf(m_r, m1);
    float sc0 = __builtin_amdgcn_exp2f(m_r - M);
    float sc1 = __builtin_amdgcn_exp2f(m1 - M);
    const float* src = (const float*)(smem + (wv >> 1) * 32768);
#pragma unroll
    for (int dt = 0; dt < 8; ++dt)
#pragma unroll
      for (int r = 0; r < 16; ++r)
        o[dt][r] = o[dt][r] * sc0 + src[(dt * 16 + r) * 64 + l] * sc1;
    l_r = l_r * sc0 + l1 * sc1;
    m_r = M;
  }
  __syncthreads();
  if (wv == 2) {                           // dump merged (2+3)
    float* dst = (float*)(smem + 32768);
#pragma unroll
    for (int dt = 0; dt < 8; ++dt)
#pragma unroll
      for (int r = 0; r < 16; ++r)
        dst[(dt * 16 + r) * 64 + l] = o[dt][r];
    ml[2 * 128 + l]      = m_r;
    ml[2 * 128 + 64 + l] = l_r;
  }
  __syncthreads();
  if (wv == 0) {
    float m1 = ml[2 * 128 + l];
    float l1 = ml[2 * 128 + 64 + l];
    float M   = fmaxf(m_r, m1);
    float sc0 = __builtin_amdgcn_exp2f(m_r - M);
    float sc1 = __builtin_amdgcn_exp2f(m1 - M);
    float lt  = l_r * sc0 + l1 * sc1;
    float inv = 1.0f / (lt * 8.0f);        // includes post-softmax /sqrt(64)
    const float* src = (const float*)(smem + 32768);
    float* chunk = (float*)smem;           // [32 q][33 d] fp32 (region 0, free now)
    float* ob = out + ((size_t)(b * T_ + q0)) * 1024;
#pragma unroll
    for (int dt = 0; dt < 8; ++dt) {
      WAIT_LGKM0();
#pragma unroll
      for (int r = 0; r < 16; ++r) {
        int dl = (r & 3) + 8 * (r >> 2) + 4 * g;
        float merged = (o[dt][r] * sc0 + src[(dt * 16 + r) * 64 + l] * sc1) * inv;
        chunk[ln * 33 + dl] = merged;
      }
      WAIT_LGKM0();
#pragma unroll
      for (int rr = 0; rr < 2; ++rr) {
        int qq = (l >> 2) + 16 * rr;
        int cp = (l & 3) * 8;
        float vv[8];
#pragma unroll
        for (int jj = 0; jj < 8; ++jj) vv[jj] = chunk[qq * 33 + cp + jj];
        float4 w0 = make_float4(vv[0], vv[1], vv[2], vv[3]);
        float4 w1 = make_float4(vv[4], vv[5], vv[6], vv[7]);
        float* orow = ob + (size_t)qq * 1024 + dt * 32 + cp;
#pragma unroll
        for (int rep = 0; rep < 4; ++rep) {
          *(float4*)(orow + rep * 256)     = w0;
          *(float4*)(orow + rep * 256 + 4) = w1;
        }
      }
    }
  }
}

extern "C" void kernel_launch(void* const* d_in, const int* in_sizes, int n_in,
                              void* d_out, int out_size, void* d_ws, size_t ws_size,
                              hipStream_t stream) {
  const float* x  = (const float*)d_in[0];
  const float* Wq = (const float*)d_in[1];
  const float* bq = (const float*)d_in[2];
  const float* Wk = (const float*)d_in[3];
  const float* bk = (const float*)d_in[4];
  const float* Wv = (const float*)d_in[5];
  const float* bv = (const float*)d_in[6];
  float* out = (float*)d_out;
  char* ws = (char*)d_ws;
  _Float16* Wt   = (_Float16*)ws;                         // 1.5 MB
  float*    bcat = (float*)(ws + 0x180000);               // 3 KB (pad to 4 KB)
  _Float16* Qh   = (_Float16*)(ws + 0x181000);            // 8 MB
  _Float16* Kh   = Qh + (size_t)16384 * 256;              // 8 MB
  _Float16* Vt   = Kh + (size_t)16384 * 256;              // 8 MB  (total ~25.6 MB)

  prep_w<<<3072, 256, 0, stream>>>(Wq, bq, Wk, bk, Wv, bv, Wt, bcat);
  qkv_gemm<<<dim3(128, 3), 256, 0, stream>>>(x, Wt, bcat, Qh, Kh, Vt);
  attn_mfma<<<512, 256, 0, stream>>>(Qh, Kh, Vt, out);
}

// Round 9
// 164.486 us; speedup vs baseline: 1.0797x; 1.0797x over previous
//
#include <hip/hip_runtime.h>
#include <float.h>
#include <stdint.h>

#define T_ 2048
#define DG 256   // folded/group width: 4 groups * 64

typedef _Float16 half8 __attribute__((ext_vector_type(8)));
typedef _Float16 half4v __attribute__((ext_vector_type(4)));
typedef __fp16 fp16x2 __attribute__((ext_vector_type(2)));
typedef float f32x4 __attribute__((ext_vector_type(4)));
typedef float f32x16 __attribute__((ext_vector_type(16)));
typedef unsigned uint2v __attribute__((ext_vector_type(2)));

__device__ __forceinline__ void gload16(const void* g, void* l) {
  __builtin_amdgcn_global_load_lds(
      (const __attribute__((address_space(1))) unsigned int*)g,
      (__attribute__((address_space(3))) unsigned int*)l, 16, 0, 0);
}
#define WAIT_VMC(N)  do { asm volatile("s_waitcnt vmcnt(" #N ")" ::: "memory"); __builtin_amdgcn_sched_barrier(0); } while (0)
#define WAIT_LGKM0() do { asm volatile("s_waitcnt lgkmcnt(0)" ::: "memory"); __builtin_amdgcn_sched_barrier(0); } while (0)

// lane<->lane^32 exchange, all-VALU (v_permlane32_swap_b32)
__device__ __forceinline__ float cross32(float x, int g) {
  unsigned u = __builtin_bit_cast(unsigned, x);
  uint2v r = __builtin_amdgcn_permlane32_swap(u, u, false, false);
  return __builtin_bit_cast(float, g ? r[0] : r[1]);
}

// ---- prep_w: Wt[768][1024] fp16 (folded Wq | Wk | Wv, transposed) + bcat[768] f32 ----
__global__ __launch_bounds__(256) void prep_w(
    const float* __restrict__ Wq, const float* __restrict__ bq,
    const float* __restrict__ Wk, const float* __restrict__ bk,
    const float* __restrict__ Wv, const float* __restrict__ bv,
    _Float16* __restrict__ Wt, float* __restrict__ bcat) {
  int idx = blockIdx.x * 256 + threadIdx.x;   // 786432
  int n = idx >> 10, k = idx & 1023;
  float v;
  if (n < 256)      v = Wq[k * 1024 + n] + Wq[k * 1024 + n + 256]
                      + Wq[k * 1024 + n + 512] + Wq[k * 1024 + n + 768];
  else if (n < 512) v = Wk[k * 256 + n - 256];
  else              v = Wv[k * 256 + n - 512];
  Wt[idx] = (_Float16)v;
  if (k == 0) {
    float bb;
    if (n < 256)      bb = bq[n] + bq[n + 256] + bq[n + 512] + bq[n + 768];
    else if (n < 512) bb = bk[n - 256];
    else              bb = bv[n - 512];
    bcat[n] = bb;
  }
}

// ---- qkv_gemm: x[16384x1024] fp32 @ Wt^T -> Q fp16(x log2e) | K fp16 | V fragment-major ----
__global__ __launch_bounds__(256) void qkv_gemm(
    const float* __restrict__ x, const _Float16* __restrict__ Wt,
    const float* __restrict__ bcat,
    _Float16* __restrict__ Qh, _Float16* __restrict__ Kh, _Float16* __restrict__ Vf) {
  __shared__ __align__(16) uint8_t smem[65536];   // 2 x (A 16KB fp32 + B 16KB fp16)
  const int tid = threadIdx.x;
  const int w = tid >> 6, l = tid & 63;
  const int wr = w >> 1, wc = w & 1;
  const int lr = l & 15, lk = l >> 4;
  const int m0 = blockIdx.x * 128;
  const int by = blockIdx.y;          // 0=Q, 1=K, 2=V
  const int n0 = by * 256;

  f32x4 acc[4][8] = {};

  auto stage = [&](int k0, int buf) {
    uint8_t* Ab = smem + buf * 32768;
    uint8_t* Bb = Ab + 16384;
#pragma unroll
    for (int i = 0; i < 4; ++i) {
      int si = i * 256 + tid;
      int row = si >> 3, p = si & 7;
      gload16(x + (size_t)(m0 + row) * 1024 + k0 + ((p ^ (row & 7)) << 2), Ab + si * 16);
    }
#pragma unroll
    for (int i = 0; i < 4; ++i) {
      int si = i * 256 + tid;
      int row = si >> 2, p = si & 3;
      gload16(Wt + (size_t)(n0 + row) * 1024 + k0 + ((p ^ (row & 3)) << 3), Bb + si * 16);
    }
  };

  stage(0, 0);
  __syncthreads();

  for (int kt = 0; kt < 32; ++kt) {
    int cur = kt & 1;
    if (kt < 31) stage((kt + 1) * 32, cur ^ 1);
    const uint8_t* Ab = smem + cur * 32768;
    const uint8_t* Bb = Ab + 16384;
    half8 af[4], bf[8];
#pragma unroll
    for (int mi = 0; mi < 4; ++mi) {
      int row = wr * 64 + mi * 16 + lr;
      const float* pa = (const float*)(Ab + row * 128);
      f32x4 a0 = *(const f32x4*)(pa + ((((lk << 1))     ^ (row & 7)) << 2));
      f32x4 a1 = *(const f32x4*)(pa + ((((lk << 1) | 1) ^ (row & 7)) << 2));
      half8 h;
#pragma unroll
      for (int j = 0; j < 4; ++j) { h[j] = (_Float16)a0[j]; h[j + 4] = (_Float16)a1[j]; }
      af[mi] = h;
    }
#pragma unroll
    for (int ni = 0; ni < 8; ++ni) {
      int row = wc * 128 + ni * 16 + lr;
      bf[ni] = *(const half8*)(Bb + row * 64 + ((lk ^ (row & 3)) << 4));
    }
#pragma unroll
    for (int mi = 0; mi < 4; ++mi)
#pragma unroll
      for (int ni = 0; ni < 8; ++ni)
        acc[mi][ni] = __builtin_amdgcn_mfma_f32_16x16x32_f16(af[mi], bf[ni], acc[mi][ni], 0, 0, 0);
    __syncthreads();
  }

  // ---- epilogue: C col = lane&15 (n), row = (lane>>4)*4 + r (m) ----
#pragma unroll
  for (int mi = 0; mi < 4; ++mi) {
#pragma unroll
    for (int ni = 0; ni < 8; ++ni) {
      int nl = wc * 128 + ni * 16 + lr;           // 0..255 within this type
      int mg = m0 + wr * 64 + mi * 16 + lk * 4;
      float bias = bcat[n0 + nl];
      if (by == 0) {
#pragma unroll
        for (int r = 0; r < 4; ++r)
          Qh[(size_t)(mg + r) * DG + nl] = (_Float16)((acc[mi][ni][r] + bias) * 1.44269504f);
      } else if (by == 1) {
#pragma unroll
        for (int r = 0; r < 4; ++r)
          Kh[(size_t)(mg + r) * DG + nl] = (_Float16)(acc[mi][ni][r] + bias);
      } else {
        // V fragment-major: [b][st][dt][half][lane=g*32+ln][8 j]
        int dt = nl >> 5, lnv = nl & 31;
        int bb = mg >> 11, t0 = mg & 2047;
        int st = t0 >> 5, sp = t0 & 31;           // sp 4-aligned
        int hs = sp >> 4, gg = (sp >> 3) & 1, j0 = sp & 7;
        size_t idx = (size_t)(((bb * 64 + st) * 8 + dt) * 2 + hs) * 512
                   + (gg * 32 + lnv) * 8 + j0;
        half4v h;
#pragma unroll
        for (int r = 0; r < 4; ++r) h[r] = (_Float16)(acc[mi][ni][r] + bias);
        *(half4v*)(Vf + idx) = h;
      }
    }
  }
}

// ---- fused causal attention: 4 waves/WG d-split over shared KV tile ----
// Wave w: QK over d-slice [64w,64w+64) (4 MFMA), LDS all-to-all score sum,
// replicated softmax, PV for output-d slice [64w,64w+64) (4 MFMA).
// K double-buffered via global_load_lds; V direct coalesced (fragment-major).
__global__ __launch_bounds__(256, 3) void attn_mfma(
    const _Float16* __restrict__ Qg, const _Float16* __restrict__ Kg,
    const _Float16* __restrict__ Vf, float* __restrict__ out) {
  __shared__ __align__(16) uint8_t smem[49152];   // K buf0 16K | K buf1 16K | Sx 16K
  const int tid = threadIdx.x;
  const int wv = tid >> 6;        // 0..3
  const int l  = tid & 63;
  const int g  = l >> 5;
  const int ln = l & 31;
  const int bid = blockIdx.x;
  const int b   = bid & 7;                 // batch -> XCD pinning
  const int tile = (bid < 256) ? (63 - (bid >> 3)) : ((bid - 256) >> 3);
  const int q0 = tile * 32;

  const _Float16* Kb  = Kg + (size_t)b * T_ * DG;
  const _Float16* Vfb = Vf + (size_t)b * 524288;
  float* Sx = (float*)(smem + 32768);

  // Q fragments for this wave's d-slice: kk_glob = 4*wv + j
  const _Float16* Qrow = Qg + ((size_t)(b * T_ + q0 + ln)) * DG + wv * 64 + 8 * g;
  half8 qf[4];
#pragma unroll
  for (int j = 0; j < 4; ++j) qf[j] = *(const half8*)(Qrow + j * 16);

  f32x16 o0 = {}, o1 = {};        // output-d blocks dt = 2wv, 2wv+1
  float m_r = -1e30f, l_r = 0.0f;

  auto stageK = [&](int s0, int buf) {
    uint8_t* Kl = smem + buf * 16384;
#pragma unroll
    for (int i = 0; i < 4; ++i) {
      int si = i * 256 + tid;
      int row = si >> 5, part = si & 31;
      gload16(Kb + (size_t)(s0 + row) * DG + ((part ^ (row & 7)) << 3), Kl + si * 16);
    }
  };

  stageK(0, 0);
  WAIT_VMC(0);
  __builtin_amdgcn_s_barrier();

  for (int kt = 0; kt <= tile; ++kt) {
    int cur = kt & 1;
    // ---- V fragments: coalesced direct loads, consumed after softmax ----
    const int dt0 = 2 * wv;
    half8 va0 = *(const half8*)(Vfb + (size_t)((kt * 8 + dt0) * 2 + 0) * 512 + l * 8);
    half8 va1 = *(const half8*)(Vfb + (size_t)((kt * 8 + dt0) * 2 + 1) * 512 + l * 8);
    half8 vb0 = *(const half8*)(Vfb + (size_t)((kt * 8 + dt0 + 1) * 2 + 0) * 512 + l * 8);
    half8 vb1 = *(const half8*)(Vfb + (size_t)((kt * 8 + dt0 + 1) * 2 + 1) * 512 + l * 8);

    // ---- partial scores over this wave's d-slice ----
    const uint8_t* Klds = smem + cur * 16384;
    const int xr = (ln & 7) << 4;
    f32x16 s_acc = {};
    __builtin_amdgcn_s_setprio(1);
#pragma unroll
    for (int j = 0; j < 4; ++j) {
      half8 kf = *(const half8*)(Klds + ln * 512 + ((((4 * wv + j) * 32) + 16 * g) ^ xr));
      s_acc = __builtin_amdgcn_mfma_f32_32x32x16_f16(kf, qf[j], s_acc, 0, 0, 0);
    }
    __builtin_amdgcn_s_setprio(0);

    // ---- publish partial, stage next K, exchange ----
#pragma unroll
    for (int r = 0; r < 16; ++r) Sx[wv * 1024 + r * 64 + l] = s_acc[r];
    if (kt < tile) stageK((kt + 1) * 32, cur ^ 1);
    WAIT_LGKM0();
    __builtin_amdgcn_s_barrier();

    float s[16];
#pragma unroll
    for (int r = 0; r < 16; ++r) s[r] = s_acc[r];
#pragma unroll
    for (int wo = 0; wo < 4; ++wo) {
      if (wo == wv) continue;
#pragma unroll
      for (int r = 0; r < 16; ++r) s[r] += Sx[wo * 1024 + r * 64 + l];
    }

    if (kt == tile) {                // causal mask, diagonal tile only
#pragma unroll
      for (int r = 0; r < 16; ++r) {
        int srow = (r & 3) + 8 * (r >> 2) + 4 * g;
        if (srow > ln) s[r] = -1e30f;
      }
    }
    // ---- softmax (replicated across waves; bit-consistent enough) ----
    float pmax = s[0];
#pragma unroll
    for (int r = 1; r < 16; ++r) pmax = fmaxf(pmax, s[r]);
    pmax = fmaxf(pmax, cross32(pmax, g));
    if (!__all(pmax <= m_r + 8.0f)) {   // defer-max rescale (T13)
      float mnew = fmaxf(m_r, pmax);
      float sc = __builtin_amdgcn_exp2f(m_r - mnew);
      l_r *= sc;
#pragma unroll
      for (int r = 0; r < 16; ++r) { o0[r] *= sc; o1[r] *= sc; }
      m_r = mnew;
    }
    float p[16]; float psum = 0.0f;
#pragma unroll
    for (int r = 0; r < 16; ++r) { p[r] = __builtin_amdgcn_exp2f(s[r] - m_r); psum += p[r]; }
    l_r += psum + cross32(psum, g);

    // ---- P -> fp16 B-fragments: cvt_pkrtz + 4 permlane32_swap ----
    unsigned ph[8];
#pragma unroll
    for (int i = 0; i < 8; ++i) {
      fp16x2 t2 = __builtin_amdgcn_cvt_pkrtz(p[2 * i], p[2 * i + 1]);
      ph[i] = __builtin_bit_cast(unsigned, t2);
    }
    union U { unsigned u[4]; half8 h; };
    U f0, f1;
    {
      uint2v r02 = __builtin_amdgcn_permlane32_swap(ph[0], ph[2], false, false);
      uint2v r13 = __builtin_amdgcn_permlane32_swap(ph[1], ph[3], false, false);
      uint2v r46 = __builtin_amdgcn_permlane32_swap(ph[4], ph[6], false, false);
      uint2v r57 = __builtin_amdgcn_permlane32_swap(ph[5], ph[7], false, false);
      f0.u[0] = r02[0]; f0.u[2] = r02[1];
      f0.u[1] = r13[0]; f0.u[3] = r13[1];
      f1.u[0] = r46[0]; f1.u[2] = r46[1];
      f1.u[1] = r57[0]; f1.u[3] = r57[1];
    }

    // ---- PV for this wave's output-d slice ----
    __builtin_amdgcn_s_setprio(1);
    o0 = __builtin_amdgcn_mfma_f32_32x32x16_f16(va0, f0.h, o0, 0, 0, 0);
    o0 = __builtin_amdgcn_mfma_f32_32x32x16_f16(va1, f1.h, o0, 0, 0, 0);
    o1 = __builtin_amdgcn_mfma_f32_32x32x16_f16(vb0, f0.h, o1, 0, 0, 0);
    o1 = __builtin_amdgcn_mfma_f32_32x32x16_f16(vb1, f1.h, o1, 0, 0, 0);
    __builtin_amdgcn_s_setprio(0);

    WAIT_VMC(0);                     // own K-stage contribution landed
    __builtin_amdgcn_s_barrier();    // K(t+1) visible to all; Sx free
  }

  // ---- epilogue: per-wave private transpose chunk in K region, 4x tiled store ----
  float inv = 1.0f / (l_r * 8.0f);   // includes post-softmax /sqrt(64)
  float* chunk = (float*)(smem + wv * 4352);   // [32 q][33 d]
  float* ob = out + ((size_t)(b * T_ + q0)) * 1024;
#pragma unroll
  for (int dtl = 0; dtl < 2; ++dtl) {
    const f32x16& oo = dtl ? o1 : o0;
    WAIT_LGKM0();
#pragma unroll
    for (int r = 0; r < 16; ++r) {
      int dl = (r & 3) + 8 * (r >> 2) + 4 * g;
      chunk[ln * 33 + dl] = oo[r] * inv;
    }
    WAIT_LGKM0();
#pragma unroll
    for (int rr = 0; rr < 2; ++rr) {
      int qq = (l >> 2) + 16 * rr;
      int cp = (l & 3) * 8;
      float vv[8];
#pragma unroll
      for (int jj = 0; jj < 8; ++jj) vv[jj] = chunk[qq * 33 + cp + jj];
      float4 w0 = make_float4(vv[0], vv[1], vv[2], vv[3]);
      float4 w1 = make_float4(vv[4], vv[5], vv[6], vv[7]);
      float* orow = ob + (size_t)qq * 1024 + (2 * wv + dtl) * 32 + cp;
#pragma unroll
      for (int rep = 0; rep < 4; ++rep) {
        *(float4*)(orow + rep * 256)     = w0;
        *(float4*)(orow + rep * 256 + 4) = w1;
      }
    }
  }
}

extern "C" void kernel_launch(void* const* d_in, const int* in_sizes, int n_in,
                              void* d_out, int out_size, void* d_ws, size_t ws_size,
                              hipStream_t stream) {
  const float* x  = (const float*)d_in[0];
  const float* Wq = (const float*)d_in[1];
  const float* bq = (const float*)d_in[2];
  const float* Wk = (const float*)d_in[3];
  const float* bk = (const float*)d_in[4];
  const float* Wv = (const float*)d_in[5];
  const float* bv = (const float*)d_in[6];
  float* out = (float*)d_out;
  char* ws = (char*)d_ws;
  _Float16* Wt   = (_Float16*)ws;                         // 1.5 MB
  float*    bcat = (float*)(ws + 0x180000);               // 3 KB (pad to 4 KB)
  _Float16* Qh   = (_Float16*)(ws + 0x181000);            // 8 MB
  _Float16* Kh   = Qh + (size_t)16384 * 256;              // 8 MB
  _Float16* Vf   = Kh + (size_t)16384 * 256;              // 8 MB fragment-major V

  prep_w<<<3072, 256, 0, stream>>>(Wq, bq, Wk, bk, Wv, bv, Wt, bcat);
  qkv_gemm<<<dim3(128, 3), 256, 0, stream>>>(x, Wt, bcat, Qh, Kh, Vf);
  attn_mfma<<<512, 256, 0, stream>>>(Qh, Kh, Vf, out);
}